// Round 3
// baseline (470.530 us; speedup 1.0000x reference)
//
#include <hip/hip_runtime.h>
#include <hip/hip_bf16.h>

// Self-attention fwd: out = softmax((xWq+bq)(xWk+bk)^T/sqrt(D)) (xWv+bv) Wo^T + bo
// Precision: split-bf16 (hi+lo, 3 MFMA products) for Q/K/scores/O-proj;
// plain bf16 for V-proj and PV (errors average through softmax weights).

typedef __attribute__((ext_vector_type(8))) short bf16x8;
typedef __attribute__((ext_vector_type(4))) float f32x4;

static __device__ __forceinline__ unsigned short f2bf(float f) {
  unsigned int u = __float_as_uint(f);
  unsigned int r = (u >> 16) & 1u;
  u += 0x7fffu + r;                 // round-to-nearest-even
  return (unsigned short)(u >> 16);
}
static __device__ __forceinline__ float bf2f(unsigned short u) {
  return __uint_as_float(((unsigned int)u) << 16);
}

static __device__ __forceinline__ void gl_lds16(const void* g, void* s) {
  __builtin_amdgcn_global_load_lds(
      (const __attribute__((address_space(1))) void*)g,
      (__attribute__((address_space(3))) void*)s, 16, 0, 0);
}

// ---------------- fp32 -> (hi, lo) bf16 split ----------------
__global__ __launch_bounds__(256) void split_f32(
    const float* __restrict__ x, unsigned short* __restrict__ hi,
    unsigned short* __restrict__ lo, int n4) {
  int i = blockIdx.x * 256 + threadIdx.x;
  if (i >= n4) return;
  float4 v = reinterpret_cast<const float4*>(x)[i];
  float vv[4] = {v.x, v.y, v.z, v.w};
  unsigned short hh[4], ll[4];
#pragma unroll
  for (int j = 0; j < 4; ++j) {
    hh[j] = f2bf(vv[j]);
    ll[j] = f2bf(vv[j] - bf2f(hh[j]));
  }
  reinterpret_cast<ushort4*>(hi)[i] = make_ushort4(hh[0], hh[1], hh[2], hh[3]);
  reinterpret_cast<ushort4*>(lo)[i] = make_ushort4(ll[0], ll[1], ll[2], ll[3]);
}

// ---------------- GEMM: C = alpha * A @ B^T (+bias) ----------------
// A: [M][K] row-major bf16 (hi[,lo]), B: [N][K] row-major bf16 (hi[,lo]).
// EPI 0: write fp32 Cf.  EPI 1: write split (Ch,Cl).  EPI 2: write bf16
// transposed per batch of S rows: Ch[b][col][row%S]  (for V^T).
#define BM 128
#define BN 128
#define BKT 32

template <bool SPLIT, int EPI>
__global__ __launch_bounds__(256) void gemm_bt(
    const unsigned short* __restrict__ Ah, const unsigned short* __restrict__ Al,
    const unsigned short* __restrict__ Bh, const unsigned short* __restrict__ Bl,
    const float* __restrict__ bias, float* __restrict__ Cf,
    unsigned short* __restrict__ Ch, unsigned short* __restrict__ Cl,
    int M, int N, int K, long sA, long sB, long sC, float alpha, int S) {
  __shared__ unsigned short lAh[BM * BKT];
  __shared__ unsigned short lBh[BN * BKT];
  __shared__ unsigned short lAl[SPLIT ? BM * BKT : 64];
  __shared__ unsigned short lBl[SPLIT ? BN * BKT : 64];

  const int tid = threadIdx.x;
  const int w = tid >> 6;
  const int lane = tid & 63;
  const int wr = w >> 1, wc = w & 1;
  const long bz = blockIdx.z;
  const long row0 = (long)blockIdx.y * BM;
  const long col0 = (long)blockIdx.x * BN;

  const unsigned short* pAh = Ah + bz * sA;
  const unsigned short* pAl = SPLIT ? (Al + bz * sA) : nullptr;
  const unsigned short* pBh = Bh + bz * sB;
  const unsigned short* pBl = SPLIT ? (Bl + bz * sB) : nullptr;

  f32x4 acc[4][4] = {};

  const int srow = tid >> 2;        // 0..63 staging row
  const int scol = (tid & 3) * 8;   // 0,8,16,24 staging col (bf16 elems)
  const int ldst0 = w * 512;        // lds elem offset for this wave (+j*2048)

  for (int k0 = 0; k0 < K; k0 += BKT) {
#pragma unroll
    for (int j = 0; j < 2; ++j) {
      const long ga = (row0 + j * 64 + srow) * (long)K + k0 + scol;
      gl_lds16(pAh + ga, &lAh[j * 2048 + ldst0]);
      if (SPLIT) gl_lds16(pAl + ga, &lAl[j * 2048 + ldst0]);
      const long gb = (col0 + j * 64 + srow) * (long)K + k0 + scol;
      gl_lds16(pBh + gb, &lBh[j * 2048 + ldst0]);
      if (SPLIT) gl_lds16(pBl + gb, &lBl[j * 2048 + ldst0]);
    }
    __syncthreads();

    const int lr = lane & 15;
    const int lk = (lane >> 4) * 8;
    bf16x8 ah[4], bh[4], al[4], bl[4];
#pragma unroll
    for (int m = 0; m < 4; ++m) {
      ah[m] = *reinterpret_cast<const bf16x8*>(&lAh[(wr * 64 + m * 16 + lr) * BKT + lk]);
      if (SPLIT)
        al[m] = *reinterpret_cast<const bf16x8*>(&lAl[(wr * 64 + m * 16 + lr) * BKT + lk]);
    }
#pragma unroll
    for (int n = 0; n < 4; ++n) {
      bh[n] = *reinterpret_cast<const bf16x8*>(&lBh[(wc * 64 + n * 16 + lr) * BKT + lk]);
      if (SPLIT)
        bl[n] = *reinterpret_cast<const bf16x8*>(&lBl[(wc * 64 + n * 16 + lr) * BKT + lk]);
    }
#pragma unroll
    for (int m = 0; m < 4; ++m)
#pragma unroll
      for (int n = 0; n < 4; ++n) {
        acc[m][n] = __builtin_amdgcn_mfma_f32_16x16x32_bf16(ah[m], bh[n], acc[m][n], 0, 0, 0);
        if (SPLIT) {
          acc[m][n] = __builtin_amdgcn_mfma_f32_16x16x32_bf16(ah[m], bl[n], acc[m][n], 0, 0, 0);
          acc[m][n] = __builtin_amdgcn_mfma_f32_16x16x32_bf16(al[m], bh[n], acc[m][n], 0, 0, 0);
        }
      }
    __syncthreads();
  }

  const int lr = lane & 15;
  const int lq = lane >> 4;
#pragma unroll
  for (int m = 0; m < 4; ++m)
#pragma unroll
    for (int n = 0; n < 4; ++n)
#pragma unroll
      for (int r = 0; r < 4; ++r) {
        const long row = row0 + wr * 64 + m * 16 + lq * 4 + r;
        const long col = col0 + wc * 64 + n * 16 + lr;
        float v = acc[m][n][r] * alpha;
        if (bias) v += bias[col];
        if (EPI == 0) {
          Cf[bz * sC + row * (long)N + col] = v;
        } else if (EPI == 1) {
          const long idx = bz * sC + row * (long)N + col;
          unsigned short h = f2bf(v);
          Ch[idx] = h;
          Cl[idx] = f2bf(v - bf2f(h));
        } else {  // EPI 2: bf16, transposed within batch of S rows
          const long b2 = row / S;
          const long rs = row - b2 * S;
          Ch[b2 * ((long)N * S) + col * (long)S + rs] = f2bf(v);
        }
      }
}

// ---------------- row softmax (in-place fp32) + bf16 copy ----------------
__global__ __launch_bounds__(256) void softmax_rows(
    float* __restrict__ Sc, unsigned short* __restrict__ P) {
  const long row = blockIdx.x;
  float* p = Sc + row * 2048;
  const int tid = threadIdx.x;
  float4 a = reinterpret_cast<float4*>(p)[tid * 2];
  float4 b = reinterpret_cast<float4*>(p)[tid * 2 + 1];
  float x[8] = {a.x, a.y, a.z, a.w, b.x, b.y, b.z, b.w};
  float m = x[0];
#pragma unroll
  for (int j = 1; j < 8; ++j) m = fmaxf(m, x[j]);
#pragma unroll
  for (int o = 32; o >= 1; o >>= 1) m = fmaxf(m, __shfl_xor(m, o));
  __shared__ float red[4], red2[4];
  if ((tid & 63) == 0) red[tid >> 6] = m;
  __syncthreads();
  m = fmaxf(fmaxf(red[0], red[1]), fmaxf(red[2], red[3]));
  float s = 0.f;
#pragma unroll
  for (int j = 0; j < 8; ++j) { x[j] = expf(x[j] - m); s += x[j]; }
#pragma unroll
  for (int o = 32; o >= 1; o >>= 1) s += __shfl_xor(s, o);
  if ((tid & 63) == 0) red2[tid >> 6] = s;
  __syncthreads();
  s = red2[0] + red2[1] + red2[2] + red2[3];
  const float inv = 1.0f / s;
#pragma unroll
  for (int j = 0; j < 8; ++j) x[j] *= inv;
  reinterpret_cast<float4*>(p)[tid * 2] = make_float4(x[0], x[1], x[2], x[3]);
  reinterpret_cast<float4*>(p)[tid * 2 + 1] = make_float4(x[4], x[5], x[6], x[7]);
  unsigned short* q = P + row * 2048;
  reinterpret_cast<ushort4*>(q)[tid * 2] =
      make_ushort4(f2bf(x[0]), f2bf(x[1]), f2bf(x[2]), f2bf(x[3]));
  reinterpret_cast<ushort4*>(q)[tid * 2 + 1] =
      make_ushort4(f2bf(x[4]), f2bf(x[5]), f2bf(x[6]), f2bf(x[7]));
}

extern "C" void kernel_launch(void* const* d_in, const int* in_sizes, int n_in,
                              void* d_out, int out_size, void* d_ws, size_t ws_size,
                              hipStream_t stream) {
  const float* x  = (const float*)d_in[0];
  const float* Wk = (const float*)d_in[1];
  const float* bk = (const float*)d_in[2];
  const float* Wq = (const float*)d_in[3];
  const float* bq = (const float*)d_in[4];
  const float* Wv = (const float*)d_in[5];
  const float* bv = (const float*)d_in[6];
  const float* Wo = (const float*)d_in[7];
  const float* bo = (const float*)d_in[8];

  float* out  = (float*)d_out;                  // [4,2048,1024]
  float* attn = (float*)d_out + 8388608;        // [4,2048,2048]

  const size_t MB = 1024 * 1024;
  unsigned char* ws = (unsigned char*)d_ws;
  unsigned short* x_hi = (unsigned short*)(ws + 0 * MB);
  unsigned short* x_lo = (unsigned short*)(ws + 16 * MB);
  unsigned short* Wk_h = (unsigned short*)(ws + 32 * MB);
  unsigned short* Wk_l = (unsigned short*)(ws + 34 * MB);
  unsigned short* Wq_h = (unsigned short*)(ws + 36 * MB);
  unsigned short* Wq_l = (unsigned short*)(ws + 38 * MB);
  unsigned short* Wv_h = (unsigned short*)(ws + 40 * MB);
  unsigned short* Wv_l = (unsigned short*)(ws + 42 * MB);
  unsigned short* Wo_h = (unsigned short*)(ws + 44 * MB);
  unsigned short* Wo_l = (unsigned short*)(ws + 46 * MB);
  unsigned short* Q_h  = (unsigned short*)(ws + 48 * MB);
  unsigned short* Q_l  = (unsigned short*)(ws + 64 * MB);
  unsigned short* K_h  = (unsigned short*)(ws + 80 * MB);
  unsigned short* K_l  = (unsigned short*)(ws + 96 * MB);
  unsigned short* Vt   = (unsigned short*)(ws + 112 * MB);  // [4][1024][2048]
  unsigned short* Pbf  = (unsigned short*)(ws + 48 * MB);   // overlays Q (after scores)
  unsigned short* at_h = (unsigned short*)(ws + 0 * MB);    // overlays x_hi (after QKV)
  unsigned short* at_l = (unsigned short*)(ws + 16 * MB);

  dim3 blk(256);

  // fp32 -> bf16 hi/lo splits
  hipLaunchKernelGGL(split_f32, dim3(8192), blk, 0, stream, x, x_hi, x_lo, 2097152);
  hipLaunchKernelGGL(split_f32, dim3(1024), blk, 0, stream, Wk, Wk_h, Wk_l, 262144);
  hipLaunchKernelGGL(split_f32, dim3(1024), blk, 0, stream, Wq, Wq_h, Wq_l, 262144);
  hipLaunchKernelGGL(split_f32, dim3(1024), blk, 0, stream, Wv, Wv_h, Wv_l, 262144);
  hipLaunchKernelGGL(split_f32, dim3(1024), blk, 0, stream, Wo, Wo_h, Wo_l, 262144);

  // Q = x@Wq^T + bq   (split output)
  hipLaunchKernelGGL((gemm_bt<true, 1>), dim3(8, 64, 1), blk, 0, stream,
                     x_hi, x_lo, Wq_h, Wq_l, bq, (float*)nullptr, Q_h, Q_l,
                     8192, 1024, 1024, 0L, 0L, 0L, 1.0f, 2048);
  // K = x@Wk^T + bk   (split output)
  hipLaunchKernelGGL((gemm_bt<true, 1>), dim3(8, 64, 1), blk, 0, stream,
                     x_hi, x_lo, Wk_h, Wk_l, bk, (float*)nullptr, K_h, K_l,
                     8192, 1024, 1024, 0L, 0L, 0L, 1.0f, 2048);
  // V = x@Wv^T + bv   (plain bf16, transposed per batch -> Vt[b][d][s])
  hipLaunchKernelGGL((gemm_bt<false, 2>), dim3(8, 64, 1), blk, 0, stream,
                     x_hi, (const unsigned short*)nullptr, Wv_h,
                     (const unsigned short*)nullptr, bv, (float*)nullptr, Vt,
                     (unsigned short*)nullptr, 8192, 1024, 1024, 0L, 0L, 0L, 1.0f, 2048);
  // scores = scale * Q@K^T  (batched, fp32 into d_out attention region)
  hipLaunchKernelGGL((gemm_bt<true, 0>), dim3(16, 16, 4), blk, 0, stream,
                     Q_h, Q_l, K_h, K_l, (const float*)nullptr, attn,
                     (unsigned short*)nullptr, (unsigned short*)nullptr,
                     2048, 2048, 1024, 2097152L, 2097152L, 4194304L, 0.03125f, 2048);
  // softmax rows (in-place fp32) + bf16 P
  hipLaunchKernelGGL(softmax_rows, dim3(8192), blk, 0, stream, attn, Pbf);
  // att_out = P @ V  (plain bf16, split output for O-proj)
  hipLaunchKernelGGL((gemm_bt<false, 1>), dim3(8, 16, 4), blk, 0, stream,
                     Pbf, (const unsigned short*)nullptr, Vt,
                     (const unsigned short*)nullptr, (const float*)nullptr,
                     (float*)nullptr, at_h, at_l,
                     2048, 1024, 2048, 4194304L, 2097152L, 2097152L, 1.0f, 2048);
  // out = att_out@Wo^T + bo  (split, fp32 into d_out)
  hipLaunchKernelGGL((gemm_bt<true, 0>), dim3(8, 64, 1), blk, 0, stream,
                     at_h, at_l, Wo_h, Wo_l, bo, out,
                     (unsigned short*)nullptr, (unsigned short*)nullptr,
                     8192, 1024, 1024, 0L, 0L, 0L, 1.0f, 2048);
}

// Round 4
// 338.225 us; speedup vs baseline: 1.3912x; 1.3912x over previous
//
#include <hip/hip_runtime.h>
#include <hip/hip_bf16.h>

// Self-attention fwd, all-FP16 single-product MFMA pipeline.
// fp16 (10-bit mantissa) gives score noise ~1.3e-4 rms; fp32 softmax; fp32 out.

typedef __attribute__((ext_vector_type(8))) _Float16 f16x8;
typedef __attribute__((ext_vector_type(4))) _Float16 f16x4;
typedef __attribute__((ext_vector_type(4))) float f32x4;

static __device__ __forceinline__ void gl_lds16(const void* g, void* s) {
  __builtin_amdgcn_global_load_lds(
      (const __attribute__((address_space(1))) void*)g,
      (__attribute__((address_space(3))) void*)s, 16, 0, 0);
}

// ---------------- fp32 -> fp16 convert ----------------
__global__ __launch_bounds__(256) void cvt16(
    const float* __restrict__ x, _Float16* __restrict__ o, int n4) {
  int i = blockIdx.x * 256 + threadIdx.x;
  if (i >= n4) return;
  float4 v = reinterpret_cast<const float4*>(x)[i];
  f16x4 r = {(_Float16)v.x, (_Float16)v.y, (_Float16)v.z, (_Float16)v.w};
  reinterpret_cast<f16x4*>(o)[i] = r;
}

// ---------------- GEMM: C = alpha * A @ B^T (+bias) ----------------
// A: [M][K] row-major fp16, B: [N][K] row-major fp16.
// EPI 0: fp32 Cf.  EPI 1: fp16 Ch.  EPI 2: fp16 transposed per batch of S
// rows: Ch[b][col][row%S]  (for V^T).
#define BM 128
#define BN 128
#define BKT 32

template <int EPI>
__global__ __launch_bounds__(256) void gemm_f16(
    const _Float16* __restrict__ A, const _Float16* __restrict__ B,
    const float* __restrict__ bias, float* __restrict__ Cf,
    _Float16* __restrict__ Ch,
    int M, int N, int K, long sA, long sB, long sC, float alpha, int S) {
  __shared__ _Float16 lA[BM * BKT];
  __shared__ _Float16 lB[BN * BKT];

  const int tid = threadIdx.x;
  const int w = tid >> 6;
  const int lane = tid & 63;
  const int wr = w >> 1, wc = w & 1;
  const long bz = blockIdx.z;
  const long row0 = (long)blockIdx.y * BM;
  const long col0 = (long)blockIdx.x * BN;

  const _Float16* pA = A + bz * sA;
  const _Float16* pB = B + bz * sB;

  f32x4 acc[4][4] = {};

  const int srow = tid >> 2;        // 0..63 staging row
  const int scol = (tid & 3) * 8;   // 0,8,16,24 staging col (fp16 elems)
  const int ldst0 = w * 512;        // lds elem offset for this wave (+j*2048)

  for (int k0 = 0; k0 < K; k0 += BKT) {
#pragma unroll
    for (int j = 0; j < 2; ++j) {
      const long ga = (row0 + j * 64 + srow) * (long)K + k0 + scol;
      gl_lds16(pA + ga, &lA[j * 2048 + ldst0]);
      const long gb = (col0 + j * 64 + srow) * (long)K + k0 + scol;
      gl_lds16(pB + gb, &lB[j * 2048 + ldst0]);
    }
    __syncthreads();

    const int lr = lane & 15;
    const int lk = (lane >> 4) * 8;
    f16x8 a[4], b[4];
#pragma unroll
    for (int m = 0; m < 4; ++m)
      a[m] = *reinterpret_cast<const f16x8*>(&lA[(wr * 64 + m * 16 + lr) * BKT + lk]);
#pragma unroll
    for (int n = 0; n < 4; ++n)
      b[n] = *reinterpret_cast<const f16x8*>(&lB[(wc * 64 + n * 16 + lr) * BKT + lk]);
#pragma unroll
    for (int m = 0; m < 4; ++m)
#pragma unroll
      for (int n = 0; n < 4; ++n)
        acc[m][n] = __builtin_amdgcn_mfma_f32_16x16x32_f16(a[m], b[n], acc[m][n], 0, 0, 0);
    __syncthreads();
  }

  const int lr = lane & 15;
  const int lq = lane >> 4;
#pragma unroll
  for (int m = 0; m < 4; ++m)
#pragma unroll
    for (int n = 0; n < 4; ++n)
#pragma unroll
      for (int r = 0; r < 4; ++r) {
        const long row = row0 + wr * 64 + m * 16 + lq * 4 + r;
        const long col = col0 + wc * 64 + n * 16 + lr;
        float v = acc[m][n][r] * alpha;
        if (bias) v += bias[col];
        if (EPI == 0) {
          Cf[bz * sC + row * (long)N + col] = v;
        } else if (EPI == 1) {
          Ch[bz * sC + row * (long)N + col] = (_Float16)v;
        } else {  // EPI 2: fp16, transposed within batch of S rows
          const long b2 = row / S;
          const long rs = row - b2 * S;
          Ch[b2 * ((long)N * S) + col * (long)S + rs] = (_Float16)v;
        }
      }
}

// ---------------- row softmax (in-place fp32) + fp16 copy ----------------
__global__ __launch_bounds__(256) void softmax_rows(
    float* __restrict__ Sc, _Float16* __restrict__ P) {
  const long row = blockIdx.x;
  float* p = Sc + row * 2048;
  const int tid = threadIdx.x;
  float4 a = reinterpret_cast<float4*>(p)[tid * 2];
  float4 b = reinterpret_cast<float4*>(p)[tid * 2 + 1];
  float x[8] = {a.x, a.y, a.z, a.w, b.x, b.y, b.z, b.w};
  float m = x[0];
#pragma unroll
  for (int j = 1; j < 8; ++j) m = fmaxf(m, x[j]);
#pragma unroll
  for (int o = 32; o >= 1; o >>= 1) m = fmaxf(m, __shfl_xor(m, o));
  __shared__ float red[4], red2[4];
  if ((tid & 63) == 0) red[tid >> 6] = m;
  __syncthreads();
  m = fmaxf(fmaxf(red[0], red[1]), fmaxf(red[2], red[3]));
  float s = 0.f;
#pragma unroll
  for (int j = 0; j < 8; ++j) { x[j] = expf(x[j] - m); s += x[j]; }
#pragma unroll
  for (int o = 32; o >= 1; o >>= 1) s += __shfl_xor(s, o);
  if ((tid & 63) == 0) red2[tid >> 6] = s;
  __syncthreads();
  s = red2[0] + red2[1] + red2[2] + red2[3];
  const float inv = 1.0f / s;
#pragma unroll
  for (int j = 0; j < 8; ++j) x[j] *= inv;
  reinterpret_cast<float4*>(p)[tid * 2] = make_float4(x[0], x[1], x[2], x[3]);
  reinterpret_cast<float4*>(p)[tid * 2 + 1] = make_float4(x[4], x[5], x[6], x[7]);
  _Float16* q = P + row * 2048;
  reinterpret_cast<f16x4*>(q)[tid * 2] =
      (f16x4){(_Float16)x[0], (_Float16)x[1], (_Float16)x[2], (_Float16)x[3]};
  reinterpret_cast<f16x4*>(q)[tid * 2 + 1] =
      (f16x4){(_Float16)x[4], (_Float16)x[5], (_Float16)x[6], (_Float16)x[7]};
}

extern "C" void kernel_launch(void* const* d_in, const int* in_sizes, int n_in,
                              void* d_out, int out_size, void* d_ws, size_t ws_size,
                              hipStream_t stream) {
  const float* x  = (const float*)d_in[0];
  const float* Wk = (const float*)d_in[1];
  const float* bk = (const float*)d_in[2];
  const float* Wq = (const float*)d_in[3];
  const float* bq = (const float*)d_in[4];
  const float* Wv = (const float*)d_in[5];
  const float* bv = (const float*)d_in[6];
  const float* Wo = (const float*)d_in[7];
  const float* bo = (const float*)d_in[8];

  float* out  = (float*)d_out;                  // [4,2048,1024]
  float* attn = (float*)d_out + 8388608;        // [4,2048,2048]

  const size_t MB = 1024 * 1024;
  unsigned char* ws = (unsigned char*)d_ws;
  _Float16* xh  = (_Float16*)(ws + 0 * MB);     // [8192][1024]      16 MB
  _Float16* Wkh = (_Float16*)(ws + 16 * MB);    //                    2 MB
  _Float16* Wqh = (_Float16*)(ws + 18 * MB);
  _Float16* Wvh = (_Float16*)(ws + 20 * MB);
  _Float16* Woh = (_Float16*)(ws + 22 * MB);
  _Float16* Qh  = (_Float16*)(ws + 24 * MB);    // [4][2048][1024]   16 MB
  _Float16* Kh  = (_Float16*)(ws + 40 * MB);    //                   16 MB
  _Float16* Vt  = (_Float16*)(ws + 56 * MB);    // [4][1024][2048]   16 MB
  _Float16* Ph  = (_Float16*)(ws + 72 * MB);    // [4][2048][2048]   32 MB
  _Float16* ath = (_Float16*)(ws + 104 * MB);   // [4][2048][1024]   16 MB

  dim3 blk(256);

  // fp32 -> fp16 conversions
  hipLaunchKernelGGL(cvt16, dim3(8192), blk, 0, stream, x, xh, 2097152);
  hipLaunchKernelGGL(cvt16, dim3(1024), blk, 0, stream, Wk, Wkh, 262144);
  hipLaunchKernelGGL(cvt16, dim3(1024), blk, 0, stream, Wq, Wqh, 262144);
  hipLaunchKernelGGL(cvt16, dim3(1024), blk, 0, stream, Wv, Wvh, 262144);
  hipLaunchKernelGGL(cvt16, dim3(1024), blk, 0, stream, Wo, Woh, 262144);

  // Q = x@Wq^T + bq
  hipLaunchKernelGGL((gemm_f16<1>), dim3(8, 64, 1), blk, 0, stream,
                     xh, Wqh, bq, (float*)nullptr, Qh,
                     8192, 1024, 1024, 0L, 0L, 0L, 1.0f, 2048);
  // K = x@Wk^T + bk
  hipLaunchKernelGGL((gemm_f16<1>), dim3(8, 64, 1), blk, 0, stream,
                     xh, Wkh, bk, (float*)nullptr, Kh,
                     8192, 1024, 1024, 0L, 0L, 0L, 1.0f, 2048);
  // V = x@Wv^T + bv, transposed per batch -> Vt[b][d][s]
  hipLaunchKernelGGL((gemm_f16<2>), dim3(8, 64, 1), blk, 0, stream,
                     xh, Wvh, bv, (float*)nullptr, Vt,
                     8192, 1024, 1024, 0L, 0L, 0L, 1.0f, 2048);
  // scores = scale * Q@K^T  (batched, fp32 into d_out attention region)
  hipLaunchKernelGGL((gemm_f16<0>), dim3(16, 16, 4), blk, 0, stream,
                     Qh, Kh, (const float*)nullptr, attn, (_Float16*)nullptr,
                     2048, 2048, 1024, 2097152L, 2097152L, 4194304L, 0.03125f, 2048);
  // softmax rows (in-place fp32) + fp16 P
  hipLaunchKernelGGL(softmax_rows, dim3(8192), blk, 0, stream, attn, Ph);
  // att_out = P @ V
  hipLaunchKernelGGL((gemm_f16<1>), dim3(8, 16, 4), blk, 0, stream,
                     Ph, Vt, (const float*)nullptr, (float*)nullptr, ath,
                     2048, 1024, 2048, 4194304L, 2097152L, 2097152L, 1.0f, 2048);
  // out = att_out@Wo^T + bo  (fp32 into d_out)
  hipLaunchKernelGGL((gemm_f16<0>), dim3(8, 64, 1), blk, 0, stream,
                     ath, Woh, bo, out, (_Float16*)nullptr,
                     8192, 1024, 1024, 0L, 0L, 0L, 1.0f, 2048);
}

// Round 5
// 281.436 us; speedup vs baseline: 1.6719x; 1.2018x over previous
//
#include <hip/hip_runtime.h>
#include <hip/hip_bf16.h>

// Self-attention fwd, all-FP16 MFMA pipeline with counted-vmcnt triple-buffered
// K-loop (stage t+2 while computing t; vmcnt(4) keeps prefetch in flight across
// the barrier) + XOR bank-conflict swizzle + fused QKV projection.

typedef __attribute__((ext_vector_type(8))) _Float16 f16x8;
typedef __attribute__((ext_vector_type(4))) _Float16 f16x4;
typedef __attribute__((ext_vector_type(4))) float f32x4;

static __device__ __forceinline__ void gl_lds16(const void* g, void* s) {
  __builtin_amdgcn_global_load_lds(
      (const __attribute__((address_space(1))) void*)g,
      (__attribute__((address_space(3))) void*)s, 16, 0, 0);
}

// slot swizzle: rows r and r+2 (mod 16) land in different banks; 2-way max (free)
static __device__ __forceinline__ int sig(int r) { return (r & 3) ^ ((r >> 2) & 3); }

// ---------------- fp32 -> fp16 convert ----------------
__global__ __launch_bounds__(256) void cvt16(
    const float* __restrict__ x, _Float16* __restrict__ o, int n4) {
  int i = blockIdx.x * 256 + threadIdx.x;
  if (i >= n4) return;
  float4 v = reinterpret_cast<const float4*>(x)[i];
  f16x4 r = {(_Float16)v.x, (_Float16)v.y, (_Float16)v.z, (_Float16)v.w};
  reinterpret_cast<f16x4*>(o)[i] = r;
}

// ---------------- bias pack (bq|bk|bv) ----------------
__global__ __launch_bounds__(256) void pack_bias(
    const float* __restrict__ bq, const float* __restrict__ bk,
    const float* __restrict__ bv, float* __restrict__ o) {
  int i = blockIdx.x * 256 + threadIdx.x;
  if (i >= 3072) return;
  o[i] = (i < 1024) ? bq[i] : (i < 2048) ? bk[i - 1024] : bv[i - 2048];
}

// ---------------- GEMM: C = alpha * A @ B^T (+bias) ----------------
// A: [M][K] fp16 row-major, B: [N][K] fp16 row-major.
// EPI 0: fp32 Cf.  EPI 1: fp16 Ch.  EPI 3: fused QKV routing
//   (col<1024 -> Ch=Q, <2048 -> C2=K, else C3=V transposed [b][d][s], S=2048).
#define BM 128
#define BN 128
#define BK 32

template <int EPI>
__global__ __launch_bounds__(256) void gemm_f16(
    const _Float16* __restrict__ A, const _Float16* __restrict__ B,
    const float* __restrict__ bias, float* __restrict__ Cf,
    _Float16* __restrict__ Ch, _Float16* __restrict__ C2,
    _Float16* __restrict__ C3,
    int M, int N, int K, long sA, long sB, long sC, float alpha) {
  __shared__ _Float16 lds[3][2][BM * BK];  // [buf][A|B][row*BK + col]

  const int tid = threadIdx.x;
  const int w = tid >> 6;
  const int lane = tid & 63;
  const int wr = w >> 1, wc = w & 1;
  const long bz = blockIdx.z;
  const long row0 = (long)blockIdx.y * BM;
  const long col0 = (long)blockIdx.x * BN;

  const _Float16* pA = A + bz * sA;
  const _Float16* pB = B + bz * sB;

  f32x4 acc[4][4] = {};

  const int srow = tid >> 2;                    // 0..63 staging row (within half)
  const int gslot = (tid & 3) ^ sig(srow);      // pre-swizzled global 16B slot
  const int lbase = (w << 4) * BK;              // wave-uniform LDS base (elems)

  const int nt = K / BK;

  // stage K-tile t into buffer b (4 x gl_lds16 per thread)
#define STAGE(b, t)                                                              \
  {                                                                              \
    const long k0 = (long)(t) * BK + gslot * 8;                                  \
    _Pragma("unroll") for (int j = 0; j < 2; ++j) {                              \
      gl_lds16(pA + (row0 + j * 64 + srow) * (long)K + k0,                       \
               &lds[b][0][j * 64 * BK + lbase]);                                 \
      gl_lds16(pB + (col0 + j * 64 + srow) * (long)K + k0,                       \
               &lds[b][1][j * 64 * BK + lbase]);                                 \
    }                                                                            \
  }

  STAGE(0, 0);
  STAGE(1, 1);
  asm volatile("s_waitcnt vmcnt(4)" ::: "memory");  // tile 0 landed
  __builtin_amdgcn_s_barrier();
  __builtin_amdgcn_sched_barrier(0);

  const int lr = lane & 15;
  const int q = lane >> 4;

  for (int t = 0; t < nt; ++t) {
    const int cur = t % 3;
    if (t + 2 < nt) STAGE((t + 2) % 3, t + 2);

    f16x8 a[4], b[4];
#pragma unroll
    for (int m = 0; m < 4; ++m) {
      const int r = wr * 64 + m * 16 + lr;
      a[m] = *reinterpret_cast<const f16x8*>(&lds[cur][0][r * BK + ((q ^ sig(r)) << 3)]);
    }
#pragma unroll
    for (int n = 0; n < 4; ++n) {
      const int r = wc * 64 + n * 16 + lr;
      b[n] = *reinterpret_cast<const f16x8*>(&lds[cur][1][r * BK + ((q ^ sig(r)) << 3)]);
    }
#pragma unroll
    for (int m = 0; m < 4; ++m)
#pragma unroll
      for (int n = 0; n < 4; ++n)
        acc[m][n] = __builtin_amdgcn_mfma_f32_16x16x32_f16(a[m], b[n], acc[m][n], 0, 0, 0);

    if (t + 2 < nt) {
      asm volatile("s_waitcnt vmcnt(4)" ::: "memory");  // t+1 landed, t+2 in flight
    } else {
      asm volatile("s_waitcnt vmcnt(0)" ::: "memory");  // epilogue drain
    }
    __builtin_amdgcn_s_barrier();
    __builtin_amdgcn_sched_barrier(0);
  }

#undef STAGE

#pragma unroll
  for (int m = 0; m < 4; ++m)
#pragma unroll
    for (int n = 0; n < 4; ++n)
#pragma unroll
      for (int r = 0; r < 4; ++r) {
        const long row = row0 + wr * 64 + m * 16 + q * 4 + r;
        const long col = col0 + wc * 64 + n * 16 + lr;
        float v = acc[m][n][r] * alpha;
        if (bias) v += bias[col];
        if (EPI == 0) {
          Cf[bz * sC + row * (long)N + col] = v;
        } else if (EPI == 1) {
          Ch[bz * sC + row * (long)N + col] = (_Float16)v;
        } else {  // EPI 3: fused QKV routing, S=2048
          if (col < 1024) {
            Ch[row * 1024 + col] = (_Float16)v;
          } else if (col < 2048) {
            C2[row * 1024 + (col - 1024)] = (_Float16)v;
          } else {
            const long b2 = row >> 11;
            const long s = row & 2047;
            C3[(b2 * 1024 + (col - 2048)) * 2048 + s] = (_Float16)v;
          }
        }
      }
}

// ---------------- row softmax (in-place fp32) + fp16 copy ----------------
__global__ __launch_bounds__(256) void softmax_rows(
    float* __restrict__ Sc, _Float16* __restrict__ P) {
  const long row = blockIdx.x;
  float* p = Sc + row * 2048;
  const int tid = threadIdx.x;
  float4 a = reinterpret_cast<float4*>(p)[tid * 2];
  float4 b = reinterpret_cast<float4*>(p)[tid * 2 + 1];
  float x[8] = {a.x, a.y, a.z, a.w, b.x, b.y, b.z, b.w};
  float m = x[0];
#pragma unroll
  for (int j = 1; j < 8; ++j) m = fmaxf(m, x[j]);
#pragma unroll
  for (int o = 32; o >= 1; o >>= 1) m = fmaxf(m, __shfl_xor(m, o));
  __shared__ float red[4], red2[4];
  if ((tid & 63) == 0) red[tid >> 6] = m;
  __syncthreads();
  m = fmaxf(fmaxf(red[0], red[1]), fmaxf(red[2], red[3]));
  float s = 0.f;
#pragma unroll
  for (int j = 0; j < 8; ++j) { x[j] = expf(x[j] - m); s += x[j]; }
#pragma unroll
  for (int o = 32; o >= 1; o >>= 1) s += __shfl_xor(s, o);
  if ((tid & 63) == 0) red2[tid >> 6] = s;
  __syncthreads();
  s = red2[0] + red2[1] + red2[2] + red2[3];
  const float inv = 1.0f / s;
#pragma unroll
  for (int j = 0; j < 8; ++j) x[j] *= inv;
  reinterpret_cast<float4*>(p)[tid * 2] = make_float4(x[0], x[1], x[2], x[3]);
  reinterpret_cast<float4*>(p)[tid * 2 + 1] = make_float4(x[4], x[5], x[6], x[7]);
  _Float16* qp = P + row * 2048;
  reinterpret_cast<f16x4*>(qp)[tid * 2] =
      (f16x4){(_Float16)x[0], (_Float16)x[1], (_Float16)x[2], (_Float16)x[3]};
  reinterpret_cast<f16x4*>(qp)[tid * 2 + 1] =
      (f16x4){(_Float16)x[4], (_Float16)x[5], (_Float16)x[6], (_Float16)x[7]};
}

extern "C" void kernel_launch(void* const* d_in, const int* in_sizes, int n_in,
                              void* d_out, int out_size, void* d_ws, size_t ws_size,
                              hipStream_t stream) {
  const float* x  = (const float*)d_in[0];
  const float* Wk = (const float*)d_in[1];
  const float* bk = (const float*)d_in[2];
  const float* Wq = (const float*)d_in[3];
  const float* bq = (const float*)d_in[4];
  const float* Wv = (const float*)d_in[5];
  const float* bv = (const float*)d_in[6];
  const float* Wo = (const float*)d_in[7];
  const float* bo = (const float*)d_in[8];

  float* out  = (float*)d_out;                  // [4,2048,1024]
  float* attn = (float*)d_out + 8388608;        // [4,2048,2048]

  const size_t MB = 1024 * 1024;
  unsigned char* ws = (unsigned char*)d_ws;
  _Float16* xh   = (_Float16*)(ws + 0 * MB);    // [8192][1024]       16 MB
  _Float16* Wf   = (_Float16*)(ws + 16 * MB);   // [3072][1024] q|k|v  6 MB
  _Float16* Woh  = (_Float16*)(ws + 22 * MB);   //                     2 MB
  float*    bqkv = (float*)   (ws + 24 * MB);   // [3072]
  _Float16* Qh   = (_Float16*)(ws + 25 * MB);   // [4][2048][1024]    16 MB
  _Float16* Kh   = (_Float16*)(ws + 41 * MB);   //                    16 MB
  _Float16* Vt   = (_Float16*)(ws + 57 * MB);   // [4][1024][2048]    16 MB
  _Float16* Ph   = (_Float16*)(ws + 73 * MB);   // [4][2048][2048]    32 MB
  _Float16* ath  = (_Float16*)(ws + 105 * MB);  // [4][2048][1024]    16 MB

  dim3 blk(256);

  // fp32 -> fp16 conversions (Wq|Wk|Wv packed contiguously)
  hipLaunchKernelGGL(cvt16, dim3(8192), blk, 0, stream, x, xh, 2097152);
  hipLaunchKernelGGL(cvt16, dim3(1024), blk, 0, stream, Wq, Wf, 262144);
  hipLaunchKernelGGL(cvt16, dim3(1024), blk, 0, stream, Wk, Wf + 1048576, 262144);
  hipLaunchKernelGGL(cvt16, dim3(1024), blk, 0, stream, Wv, Wf + 2097152, 262144);
  hipLaunchKernelGGL(cvt16, dim3(1024), blk, 0, stream, Wo, Woh, 262144);
  hipLaunchKernelGGL(pack_bias, dim3(12), blk, 0, stream, bq, bk, bv, bqkv);

  // fused QKV: [Q|K|V] = x@[Wq|Wk|Wv]^T + b  (V written transposed per batch)
  hipLaunchKernelGGL((gemm_f16<3>), dim3(24, 64, 1), blk, 0, stream,
                     xh, Wf, bqkv, (float*)nullptr, Qh, Kh, Vt,
                     8192, 3072, 1024, 0L, 0L, 0L, 1.0f);
  // scores = scale * Q@K^T  (batched, fp32 into d_out attention region)
  hipLaunchKernelGGL((gemm_f16<0>), dim3(16, 16, 4), blk, 0, stream,
                     Qh, Kh, (const float*)nullptr, attn,
                     (_Float16*)nullptr, (_Float16*)nullptr, (_Float16*)nullptr,
                     2048, 2048, 1024, 2097152L, 2097152L, 4194304L, 0.03125f);
  // softmax rows (in-place fp32) + fp16 P
  hipLaunchKernelGGL(softmax_rows, dim3(8192), blk, 0, stream, attn, Ph);
  // att_out = P @ V
  hipLaunchKernelGGL((gemm_f16<1>), dim3(8, 16, 4), blk, 0, stream,
                     Ph, Vt, (const float*)nullptr, (float*)nullptr, ath,
                     (_Float16*)nullptr, (_Float16*)nullptr,
                     2048, 1024, 2048, 4194304L, 2097152L, 2097152L, 1.0f);
  // out = att_out@Wo^T + bo  (fp32 into d_out)
  hipLaunchKernelGGL((gemm_f16<0>), dim3(8, 64, 1), blk, 0, stream,
                     ath, Woh, bo, out,
                     (_Float16*)nullptr, (_Float16*)nullptr, (_Float16*)nullptr,
                     8192, 1024, 1024, 0L, 0L, 0L, 1.0f);
}